// Round 18
// baseline (269.743 us; speedup 1.0000x reference)
//
#include <hip/hip_runtime.h>
#include <hip/hip_bf16.h>
#include <stdint.h>

typedef unsigned short u16;
typedef short bf16x8 __attribute__((ext_vector_type(8)));
typedef float f32x4 __attribute__((ext_vector_type(4)));
typedef u16 u16x8 __attribute__((ext_vector_type(8)));

#define DEVFN static __device__ __forceinline__

// sizes
#define NB 16
#define CIN 256
#define HH 64
#define WW 64
#define COUT 512
#define NPX 4096           // 64*64
#define NSTEP 72           // 8 ci-blocks * 9 shifts

DEVFN u16 bf16_rne(float f){
  union { float f; uint32_t u; } v; v.f = f;
  uint32_t u = v.u;
  return (u16)((u + 0x7fffu + ((u >> 16) & 1u)) >> 16);
}

DEVFN void gload16(const void* g, void* l){
  __builtin_amdgcn_global_load_lds((const __attribute__((address_space(1))) void*)g,
                                   (__attribute__((address_space(3))) void*)l,
                                   16, 0, 0);
}

#define VMWAIT(N) asm volatile("s_waitcnt vmcnt(" #N ")" ::: "memory")
#define LGKM0() do { asm volatile("s_waitcnt lgkmcnt(0)" ::: "memory"); \
                     __builtin_amdgcn_sched_barrier(0); } while(0)
#define BARRIER() do { __builtin_amdgcn_s_barrier(); \
                       __builtin_amdgcn_sched_barrier(0); \
                       asm volatile("" ::: "memory"); } while(0)

// ---------------- routing = sigmoid((pooled_sum/4096) @ fcw^T + fcb) ----------------
__global__ void k_route(const float* __restrict__ pooled, const float* __restrict__ fcw,
                        const float* __restrict__ fcb, float* __restrict__ routing){
  int bk = blockIdx.x;              // 0..127
  int b = bk >> 3, k = bk & 7;
  int l = threadIdx.x;              // 64
  float4 pv = ((const float4*)(pooled + b*CIN))[l];
  float4 wv = ((const float4*)(fcw   + k*CIN))[l];
  float s = pv.x*wv.x + pv.y*wv.y + pv.z*wv.z + pv.w*wv.w;
  for (int o = 32; o; o >>= 1) s += __shfl_down(s, o);
  if (l == 0) routing[b*8 + k] = 1.0f / (1.0f + __expf(-(s * (1.0f/(float)NPX) + fcb[k])));
}

// ---------------- combined bias ----------------
__global__ void k_cbias(const float* __restrict__ routing, const float* __restrict__ eb,
                        float* __restrict__ cbias){
  int idx = blockIdx.x*256 + threadIdx.x;   // 8192 = b*512+co
  int b = idx >> 9, co = idx & 511;
  float s = 0.f;
  for (int k = 0; k < 8; k++) s += routing[b*8+k] * eb[k*COUT + co];
  cbias[idx] = s;
}

// ---------------- combined weights -> bf16, layout [b][step][co][ci32] ----------------
__global__ void k_wcomb(const float* __restrict__ routing, const float* __restrict__ ew,
                        u16* __restrict__ wc){
  int blk  = blockIdx.x;            // 72*64 = 4608
  int step = blk >> 6;              // 0..71
  int cog  = blk & 63;
  int cb = step / 9, rs = step - cb*9;
  int t = threadIdx.x;
  int ci = t & 31, co = cog*8 + (t >> 5);
  int cig = cb*32 + ci;
  float wv[8];
#pragma unroll
  for (int k = 0; k < 8; k++)
    wv[k] = ew[(size_t)((k*COUT + co)*CIN + cig)*9 + rs];
  for (int b = 0; b < NB; b++){
    float s = 0.f;
#pragma unroll
    for (int k = 0; k < 8; k++) s += routing[b*8+k] * wv[k];
    wc[((size_t)(b*NSTEP + step)*COUT + co)*32 + ci] = bf16_rne(s);
  }
}

// ---------------- zero only the halo of x_t ----------------
__global__ void k_halo(u16* __restrict__ xt){
  int blk = blockIdx.x;             // 16*66 = 1056
  int b = blk / 66, row = blk - b*66;
  uint32_t* base = (uint32_t*)(xt + ((size_t)(b*66 + row))*68*256);
  int t = threadIdx.x;
  if (row == 0 || row == 65){
    for (int i = t; i < 8704; i += 256) base[i] = 0;
  } else {
    for (int i = t; i < 512; i += 256){
      int idx = (i < 128) ? i : (8320 + (i - 128));   // col 0 ; cols 65..67
      base[idx] = 0;
    }
  }
}

// ---- x -> padded transposed bf16 x_t[b][66][68][256]  +  fused GAP partials ----
__global__ void k_xprep(const float* __restrict__ x, u16* __restrict__ xt,
                        float* __restrict__ pooled){
  int blk = blockIdx.x;             // 16*64*4 = 4096
  int ctile = blk & 3;
  int h = (blk >> 2) & 63;
  int b = blk >> 8;
  __shared__ u16 S[64][66];
  int t = threadIdx.x;
  {
    int ci_l = t >> 2, w0 = (t & 3) * 16;
    const float4* src = (const float4*)(x + ((size_t)((b*CIN + ctile*64 + ci_l)*HH + h)*WW + w0));
    float4 a = src[0], bb = src[1], c = src[2], d = src[3];
    u16* row = &S[ci_l][w0];
    row[0]=bf16_rne(a.x);  row[1]=bf16_rne(a.y);  row[2]=bf16_rne(a.z);  row[3]=bf16_rne(a.w);
    row[4]=bf16_rne(bb.x); row[5]=bf16_rne(bb.y); row[6]=bf16_rne(bb.z); row[7]=bf16_rne(bb.w);
    row[8]=bf16_rne(c.x);  row[9]=bf16_rne(c.y);  row[10]=bf16_rne(c.z); row[11]=bf16_rne(c.w);
    row[12]=bf16_rne(d.x); row[13]=bf16_rne(d.y); row[14]=bf16_rne(d.z); row[15]=bf16_rne(d.w);
    float s = a.x+a.y+a.z+a.w + bb.x+bb.y+bb.z+bb.w + c.x+c.y+c.z+c.w + d.x+d.y+d.z+d.w;
    s += __shfl_down(s, 2);
    s += __shfl_down(s, 1);
    if ((t & 3) == 0) atomicAdd(&pooled[b*CIN + ctile*64 + ci_l], s);
  }
  __syncthreads();
  {
    int w_l = t >> 2, cig = (t & 3) * 16;
    u16x8 v0, v1;
#pragma unroll
    for (int j = 0; j < 8; j++){ v0[j] = S[cig+j][w_l]; v1[j] = S[cig+8+j][w_l]; }
    u16* dst = xt + ((size_t)(b*66 + h + 1)*68 + (w_l + 1))*CIN + ctile*64 + cig;
    *(u16x8*)(dst)     = v0;
    *(u16x8*)(dst + 8) = v1;
  }
}

// -------- conv: R15 base; ph1 MFMA hoisted ABOVE vmwait+barrier; 1 barrier/step.
// -------- Block 256px x 256co, 512 thr, 8 waves of 128px x 64co.  W ring-3, X dbuf.
#define WBYTES 16384      // 256co*32ci*2
#define XBYTES 26112      // 6*68*32*2

// one half (512 chunks) of a 256co x 32ci W tile; 1 chunk/lane
template<int H>
DEVFN void stage_w_half(const u16* __restrict__ wstep, char* dst, int wv, int l){
  int qb = H*512 + wv*64;
  int q  = qb + l;
  int co_l = q >> 2, j = q & 3;
  gload16(wstep + co_l*32 + ((j ^ ((co_l >> 1) & 3)) << 3), dst + qb*16);
  __builtin_amdgcn_sched_barrier(0);
}

// one quarter (chunk C of 4) of a 6row x 68col x 32ci X tile (1632 chunks, dup-wrap)
template<int C>
DEVFN void stage_x_chunk(const u16* __restrict__ xtb, int h0, int cioff, char* dst,
                         int wv, int l){
  int qb = C*512 + wv*64;
  if (qb >= 1632) qb -= 1632;          // wave-uniform dup (same data, benign)
  int q = qb + l;
  int t2 = q >> 2;                     // 0..407 = row*68+col
  int lr = (t2 * 964) >> 16;           // /68, exact for t2<408
  int c  = t2 - lr*68;
  int j  = q & 3;
  gload16(xtb + ((size_t)(h0 + lr)*68 + c)*CIN + cioff + ((j ^ ((c >> 1) & 3)) << 3),
          dst + qb*16);
  __builtin_amdgcn_sched_barrier(0);
}

// one K=32 step t=cb*9+RS, ONE barrier, MFMA-before-wait:
//  ph0 (barrier-free): reads W(t)+X rows -> stage h0(W t+2) -> LGKM0 -> 16 MFMA
//  ph1: reads X rows -> stage h1 (+X chunk) -> LGKM0 -> 16 MFMA -> VMWAIT(2) -> BARRIER
// At the barrier every wave has retired its step-t LDS reads (LGKM0 before MFMA,
// program order) and W(t+1)'s stages (vmwait) -> the single barrier both publishes
// W(t+1)/X chunks and guards the slot overwrite at t+1.  The vmwait drains UNDER
// the 16-MFMA cluster; no trailing compute after the barrier.
template<int RS>
DEVFN void conv_step(int cb, char* ldsW, const char* Xc, char* Xn,
                     const u16* __restrict__ xtb, const u16* __restrict__ wcb, int h0,
                     int wv, int l, int wm, int wn, int l15, int kbq,
                     f32x4 acc[4][8])
{
  constexpr int r = RS/3, s = RS - r*3;
  const char* Wc = ldsW + (RS % 3)*WBYTES;
  char* Wp       = ldsW + ((RS + 2) % 3)*WBYTES;
  const u16* wnext = wcb + (size_t)(cb*9 + RS + 2)*(COUT*32);
  const bool dostage = (RS <= 6) || (cb < 7);

  // ---- phase 0 (no barriers) ----
  bf16x8 wf[4], xf[4];
  const int swzA = (kbq ^ ((l15 >> 1) & 3)) << 4;
#pragma unroll
  for (int nf = 0; nf < 4; nf++)
    wf[nf] = *(const bf16x8*)(Wc + (wn*64 + nf*16 + l15)*64 + swzA);
  {
    int row = wm*2 + r;
#pragma unroll
    for (int mf = 0; mf < 4; mf++){
      int c0 = mf*16 + l15 + s;
      xf[mf] = *(const bf16x8*)(Xc + (row*68 + c0)*64 + ((kbq ^ ((c0 >> 1) & 3)) << 4));
    }
  }
  if (dostage) stage_w_half<0>(wnext, Wp, wv, l);
  LGKM0();                         // own reads landed (rule #18)
  __builtin_amdgcn_s_setprio(1);
#pragma unroll
  for (int nf = 0; nf < 4; nf++)
#pragma unroll
    for (int mf = 0; mf < 4; mf++)
      acc[nf][mf] = __builtin_amdgcn_mfma_f32_16x16x32_bf16(wf[nf], xf[mf], acc[nf][mf], 0, 0, 0);
  __builtin_amdgcn_s_setprio(0);

  // ---- phase 1: reads, stage, MFMA, THEN wait+barrier ----
  {
    int row = wm*2 + 1 + r;
#pragma unroll
    for (int mf = 0; mf < 4; mf++){
      int c0 = mf*16 + l15 + s;
      xf[mf] = *(const bf16x8*)(Xc + (row*68 + c0)*64 + ((kbq ^ ((c0 >> 1) & 3)) << 4));
    }
  }
  if (dostage) stage_w_half<1>(wnext, Wp, wv, l);
  if constexpr (RS <= 3) { if (cb < 7) stage_x_chunk<RS>(xtb, h0, (cb+1)*32, Xn, wv, l); }
  LGKM0();                         // retire own step-t LDS reads before MFMA/barrier
  __builtin_amdgcn_s_setprio(1);
#pragma unroll
  for (int nf = 0; nf < 4; nf++)
#pragma unroll
    for (int mf = 0; mf < 4; mf++)
      acc[nf][mf+4] = __builtin_amdgcn_mfma_f32_16x16x32_bf16(wf[nf], xf[mf], acc[nf][mf+4], 0, 0, 0);
  __builtin_amdgcn_s_setprio(0);
  // FIFO identical to R12/R15: keep 2 newest in flight; W(t+1) fully retired.
  if (dostage) { VMWAIT(2); }
  else if constexpr (RS == 7) { VMWAIT(0); }
  BARRIER();                       // publish W(t+1)(+X chunks); overwrite-guard
}

__global__ __launch_bounds__(512, 2) void k_conv(
    const u16* __restrict__ xt, const u16* __restrict__ wc,
    const float* __restrict__ cbias, float* __restrict__ out, u16* __restrict__ obf,
    float* __restrict__ ssum, float* __restrict__ ssq)
{
  __shared__ char lds[3*WBYTES + 2*XBYTES];   // 101376 -> 1 block/CU
  char* XA = lds + 3*WBYTES;
  char* XB = lds + 3*WBYTES + XBYTES;

  // XCD-contiguous mapping: 512 blocks; xcd owns 2 samples, sample-major order.
  int hw  = blockIdx.x;
  int xcd = hw & 7;
  int i   = hw >> 3;                 // 0..63
  int b   = xcd*2 + (i >> 5);
  int ct  = (i >> 4) & 1;
  int pt  = i & 15;
  int h0  = pt * 4;

  int t = threadIdx.x, l = t & 63, wv = t >> 6;   // 8 waves
  int wm = wv >> 2, wn = wv & 3;                  // px-half, co-quarter
  int l15 = l & 15, kbq = l >> 4;

  const u16* xtb = xt + (size_t)b * 66*68*CIN;
  const u16* wcb = wc + (size_t)(b*NSTEP) * COUT*32 + ct*256*32;

  f32x4 acc[4][8];
#pragma unroll
  for (int nf = 0; nf < 4; nf++)
#pragma unroll
    for (int mf = 0; mf < 8; mf++) acc[nf][mf] = (f32x4){0.f,0.f,0.f,0.f};

  // prologue: X(0)->XA (4 chunks), W(0)->slot0, W(1)->slot1; drain; publish.
  stage_x_chunk<0>(xtb, h0, 0, XA, wv, l);
  stage_x_chunk<1>(xtb, h0, 0, XA, wv, l);
  stage_x_chunk<2>(xtb, h0, 0, XA, wv, l);
  stage_x_chunk<3>(xtb, h0, 0, XA, wv, l);
  stage_w_half<0>(wcb,           lds + 0*WBYTES, wv, l);
  stage_w_half<1>(wcb,           lds + 0*WBYTES, wv, l);
  stage_w_half<0>(wcb + COUT*32, lds + 1*WBYTES, wv, l);
  stage_w_half<1>(wcb + COUT*32, lds + 1*WBYTES, wv, l);
  VMWAIT(0);
  BARRIER();

  for (int cb = 0; cb < 8; cb++){
    const char* Xc = (cb & 1) ? XB : XA;
    char*       Xn = (cb & 1) ? XA : XB;
    conv_step<0>(cb, lds, Xc, Xn, xtb, wcb, h0, wv,l,wm,wn,l15,kbq, acc);
    conv_step<1>(cb, lds, Xc, Xn, xtb, wcb, h0, wv,l,wm,wn,l15,kbq, acc);
    conv_step<2>(cb, lds, Xc, Xn, xtb, wcb, h0, wv,l,wm,wn,l15,kbq, acc);
    conv_step<3>(cb, lds, Xc, Xn, xtb, wcb, h0, wv,l,wm,wn,l15,kbq, acc);
    conv_step<4>(cb, lds, Xc, Xn, xtb, wcb, h0, wv,l,wm,wn,l15,kbq, acc);
    conv_step<5>(cb, lds, Xc, Xn, xtb, wcb, h0, wv,l,wm,wn,l15,kbq, acc);
    conv_step<6>(cb, lds, Xc, Xn, xtb, wcb, h0, wv,l,wm,wn,l15,kbq, acc);
    conv_step<7>(cb, lds, Xc, Xn, xtb, wcb, h0, wv,l,wm,wn,l15,kbq, acc);
    conv_step<8>(cb, lds, Xc, Xn, xtb, wcb, h0, wv,l,wm,wn,l15,kbq, acc);
  }

  // ---- epilogue: bias add, store bf16 (or f32), fused BN partials ----
#pragma unroll
  for (int nf = 0; nf < 4; nf++){
#pragma unroll
    for (int rg = 0; rg < 4; rg++){
      int co = ct*256 + wn*64 + nf*16 + (kbq << 2) + rg;
      float bias = cbias[b*COUT + co];
      float s1 = 0.f, s2 = 0.f;
      size_t base = ((size_t)b * COUT + co) * NPX;
#pragma unroll
      for (int mf = 0; mf < 8; mf++){
        float v = acc[nf][mf][rg] + bias;
        int px = (h0 + wm*2 + (mf >> 2))*64 + (mf & 3)*16 + l15;
        if (obf) obf[base + px] = bf16_rne(v);
        else     out[base + px] = v;
        s1 += v; s2 += v*v;
      }
#pragma unroll
      for (int o = 8; o; o >>= 1){ s1 += __shfl_xor(s1, o); s2 += __shfl_xor(s2, o); }
      if (l15 == 0){ atomicAdd(&ssum[co], s1); atomicAdd(&ssq[co], s2); }
    }
  }
}

// ---------------- finalize BN scale/shift ----------------
__global__ void k_stats(const float* __restrict__ ssum, const float* __restrict__ ssq,
                        const float* __restrict__ gamma, const float* __restrict__ beta,
                        float* __restrict__ sc, float* __restrict__ sh){
  int co = blockIdx.x*256 + threadIdx.x;    // 512
  const float invN = 1.0f / 65536.0f;
  float m  = ssum[co] * invN;
  float var = ssq[co] * invN - m*m;
  float scale = gamma[co] * rsqrtf(var + 1e-5f);
  sc[co] = scale;
  sh[co] = beta[co] - m*scale;
}

// ---------------- normalize + LeakyReLU: f32 in-place variant ----------------
__global__ void k_norm(float* __restrict__ out, const float* __restrict__ sc,
                       const float* __restrict__ sh){
  const int NF4 = (NB*COUT*NPX)/4;          // 8388608
  int idx = blockIdx.x*256 + threadIdx.x;
  float4* o4 = (float4*)out;
  for (int i = idx; i < NF4; i += 2048*256){
    float4 v = o4[i];
    int co = (i >> 10) & 511;
    float a = sc[co], d = sh[co];
    v.x = fmaf(v.x, a, d); v.y = fmaf(v.y, a, d);
    v.z = fmaf(v.z, a, d); v.w = fmaf(v.w, a, d);
    v.x = v.x > 0.f ? v.x : 0.1f*v.x;
    v.y = v.y > 0.f ? v.y : 0.1f*v.y;
    v.z = v.z > 0.f ? v.z : 0.1f*v.z;
    v.w = v.w > 0.f ? v.w : 0.1f*v.w;
    o4[i] = v;
  }
}

// ---------------- normalize + LeakyReLU: bf16 -> f32 variant ----------------
__global__ void k_norm_bf16(const u16* __restrict__ obf, float* __restrict__ out,
                            const float* __restrict__ sc, const float* __restrict__ sh){
  const int NG = (NB*COUT*NPX)/8;           // 4194304
  int idx = blockIdx.x*256 + threadIdx.x;
  for (int g = idx; g < NG; g += 2048*256){
    u16x8 v = *(const u16x8*)(obf + (size_t)g*8);
    int co = (g >> 9) & 511;
    float a = sc[co], d = sh[co];
    float vv[8];
#pragma unroll
    for (int j = 0; j < 8; j++){
      union{ uint32_t u; float f; } c; c.u = ((uint32_t)(u16)v[j]) << 16;
      float w = fmaf(c.f, a, d);
      vv[j] = w > 0.f ? w : 0.1f*w;
    }
    float4* o4 = (float4*)(out + (size_t)g*8);
    o4[0] = (float4){vv[0],vv[1],vv[2],vv[3]};
    o4[1] = (float4){vv[4],vv[5],vv[6],vv[7]};
  }
}

extern "C" void kernel_launch(void* const* d_in, const int* in_sizes, int n_in,
                              void* d_out, int out_size, void* d_ws, size_t ws_size,
                              hipStream_t stream) {
  const float* x     = (const float*)d_in[0];
  const float* ew    = (const float*)d_in[1];
  const float* eb    = (const float*)d_in[2];
  const float* fcw   = (const float*)d_in[3];
  const float* fcb   = (const float*)d_in[4];
  const float* gamma = (const float*)d_in[5];
  const float* beta  = (const float*)d_in[6];
  float* out = (float*)d_out;

  char* ws = (char*)d_ws;
  const size_t XT_BYTES  = (size_t)NB*66*68*CIN*2;         // 36,765,696
  const size_t WC_BYTES  = (size_t)NB*NSTEP*COUT*32*2;     // 37,748,736
  const size_t FL_BYTES  = 65536;
  const size_t OBF_BYTES = (size_t)NB*COUT*NPX*2;          // 67,108,864
  u16* xt = (u16*)ws;
  u16* wc = (u16*)(ws + XT_BYTES);
  float* fbase   = (float*)(ws + XT_BYTES + WC_BYTES);
  float* pooled  = fbase;                 // 4096 (zeroed)
  float* ssum    = fbase + 4096;          // 512  (zeroed)
  float* ssq     = fbase + 4608;          // 512  (zeroed)
  float* routing = fbase + 5120;          // 128
  float* cbias   = fbase + 5248;          // 8192
  float* sc      = fbase + 13440;         // 512
  float* sh      = fbase + 13952;         // 512
  bool use_bf16 = ws_size >= XT_BYTES + WC_BYTES + FL_BYTES + OBF_BYTES;
  u16* obf = use_bf16 ? (u16*)(ws + XT_BYTES + WC_BYTES + FL_BYTES) : (u16*)nullptr;

  hipMemsetAsync(pooled, 0, 5120*sizeof(float), stream);   // pooled+ssum+ssq

  k_halo <<<1056, 256, 0, stream>>>(xt);
  k_xprep<<<4096, 256, 0, stream>>>(x, xt, pooled);
  k_route<<<128,   64, 0, stream>>>(pooled, fcw, fcb, routing);
  k_cbias<<<32,   256, 0, stream>>>(routing, eb, cbias);
  k_wcomb<<<4608, 256, 0, stream>>>(routing, ew, wc);
  k_conv <<<512,  512, 0, stream>>>(xt, wc, cbias, out, obf, ssum, ssq);
  k_stats<<<2,    256, 0, stream>>>(ssum, ssq, gamma, beta, sc, sh);
  if (use_bf16) k_norm_bf16<<<2048, 256, 0, stream>>>(obf, out, sc, sh);
  else          k_norm     <<<2048, 256, 0, stream>>>(out, sc, sh);
}

// Round 19
// 266.407 us; speedup vs baseline: 1.0125x; 1.0125x over previous
//
#include <hip/hip_runtime.h>
#include <hip/hip_bf16.h>
#include <stdint.h>

typedef unsigned short u16;
typedef short bf16x8 __attribute__((ext_vector_type(8)));
typedef float f32x4 __attribute__((ext_vector_type(4)));
typedef u16 u16x8 __attribute__((ext_vector_type(8)));

#define DEVFN static __device__ __forceinline__

// sizes
#define NB 16
#define CIN 256
#define HH 64
#define WW 64
#define COUT 512
#define NPX 4096           // 64*64
#define NSTEP 72           // 8 ci-blocks * 9 shifts

DEVFN u16 bf16_rne(float f){
  union { float f; uint32_t u; } v; v.f = f;
  uint32_t u = v.u;
  return (u16)((u + 0x7fffu + ((u >> 16) & 1u)) >> 16);
}

DEVFN void gload16(const void* g, void* l){
  __builtin_amdgcn_global_load_lds((const __attribute__((address_space(1))) void*)g,
                                   (__attribute__((address_space(3))) void*)l,
                                   16, 0, 0);
}

#define VMWAIT(N) asm volatile("s_waitcnt vmcnt(" #N ")" ::: "memory")
#define LGKM0() do { asm volatile("s_waitcnt lgkmcnt(0)" ::: "memory"); \
                     __builtin_amdgcn_sched_barrier(0); } while(0)
#define BARRIER() do { __builtin_amdgcn_s_barrier(); \
                       __builtin_amdgcn_sched_barrier(0); \
                       asm volatile("" ::: "memory"); } while(0)

// ---------------- routing = sigmoid((pooled_sum/4096) @ fcw^T + fcb) ----------------
__global__ void k_route(const float* __restrict__ pooled, const float* __restrict__ fcw,
                        const float* __restrict__ fcb, float* __restrict__ routing){
  int bk = blockIdx.x;              // 0..127
  int b = bk >> 3, k = bk & 7;
  int l = threadIdx.x;              // 64
  float4 pv = ((const float4*)(pooled + b*CIN))[l];
  float4 wv = ((const float4*)(fcw   + k*CIN))[l];
  float s = pv.x*wv.x + pv.y*wv.y + pv.z*wv.z + pv.w*wv.w;
  for (int o = 32; o; o >>= 1) s += __shfl_down(s, o);
  if (l == 0) routing[b*8 + k] = 1.0f / (1.0f + __expf(-(s * (1.0f/(float)NPX) + fcb[k])));
}

// ---------------- combined bias ----------------
__global__ void k_cbias(const float* __restrict__ routing, const float* __restrict__ eb,
                        float* __restrict__ cbias){
  int idx = blockIdx.x*256 + threadIdx.x;   // 8192 = b*512+co
  int b = idx >> 9, co = idx & 511;
  float s = 0.f;
  for (int k = 0; k < 8; k++) s += routing[b*8+k] * eb[k*COUT + co];
  cbias[idx] = s;
}

// ---------------- combined weights -> bf16, layout [b][step][co][ci32] ----------------
__global__ void k_wcomb(const float* __restrict__ routing, const float* __restrict__ ew,
                        u16* __restrict__ wc){
  int blk  = blockIdx.x;            // 72*64 = 4608
  int step = blk >> 6;              // 0..71
  int cog  = blk & 63;
  int cb = step / 9, rs = step - cb*9;
  int t = threadIdx.x;
  int ci = t & 31, co = cog*8 + (t >> 5);
  int cig = cb*32 + ci;
  float wv[8];
#pragma unroll
  for (int k = 0; k < 8; k++)
    wv[k] = ew[(size_t)((k*COUT + co)*CIN + cig)*9 + rs];
  for (int b = 0; b < NB; b++){
    float s = 0.f;
#pragma unroll
    for (int k = 0; k < 8; k++) s += routing[b*8+k] * wv[k];
    wc[((size_t)(b*NSTEP + step)*COUT + co)*32 + ci] = bf16_rne(s);
  }
}

// ---------------- zero only the halo of x_t ----------------
__global__ void k_halo(u16* __restrict__ xt){
  int blk = blockIdx.x;             // 16*66 = 1056
  int b = blk / 66, row = blk - b*66;
  uint32_t* base = (uint32_t*)(xt + ((size_t)(b*66 + row))*68*256);
  int t = threadIdx.x;
  if (row == 0 || row == 65){
    for (int i = t; i < 8704; i += 256) base[i] = 0;
  } else {
    for (int i = t; i < 512; i += 256){
      int idx = (i < 128) ? i : (8320 + (i - 128));   // col 0 ; cols 65..67
      base[idx] = 0;
    }
  }
}

// ---- x -> padded transposed bf16 x_t[b][66][68][256]  +  fused GAP partials ----
__global__ void k_xprep(const float* __restrict__ x, u16* __restrict__ xt,
                        float* __restrict__ pooled){
  int blk = blockIdx.x;             // 16*64*4 = 4096
  int ctile = blk & 3;
  int h = (blk >> 2) & 63;
  int b = blk >> 8;
  __shared__ u16 S[64][66];
  int t = threadIdx.x;
  {
    int ci_l = t >> 2, w0 = (t & 3) * 16;
    const float4* src = (const float4*)(x + ((size_t)((b*CIN + ctile*64 + ci_l)*HH + h)*WW + w0));
    float4 a = src[0], bb = src[1], c = src[2], d = src[3];
    u16* row = &S[ci_l][w0];
    row[0]=bf16_rne(a.x);  row[1]=bf16_rne(a.y);  row[2]=bf16_rne(a.z);  row[3]=bf16_rne(a.w);
    row[4]=bf16_rne(bb.x); row[5]=bf16_rne(bb.y); row[6]=bf16_rne(bb.z); row[7]=bf16_rne(bb.w);
    row[8]=bf16_rne(c.x);  row[9]=bf16_rne(c.y);  row[10]=bf16_rne(c.z); row[11]=bf16_rne(c.w);
    row[12]=bf16_rne(d.x); row[13]=bf16_rne(d.y); row[14]=bf16_rne(d.z); row[15]=bf16_rne(d.w);
    float s = a.x+a.y+a.z+a.w + bb.x+bb.y+bb.z+bb.w + c.x+c.y+c.z+c.w + d.x+d.y+d.z+d.w;
    s += __shfl_down(s, 2);
    s += __shfl_down(s, 1);
    if ((t & 3) == 0) atomicAdd(&pooled[b*CIN + ctile*64 + ci_l], s);
  }
  __syncthreads();
  {
    int w_l = t >> 2, cig = (t & 3) * 16;
    u16x8 v0, v1;
#pragma unroll
    for (int j = 0; j < 8; j++){ v0[j] = S[cig+j][w_l]; v1[j] = S[cig+8+j][w_l]; }
    u16* dst = xt + ((size_t)(b*66 + h + 1)*68 + (w_l + 1))*CIN + ctile*64 + cig;
    *(u16x8*)(dst)     = v0;
    *(u16x8*)(dst + 8) = v1;
  }
}

// -------- conv (FINAL = R15): m201-style 2-phase steps, phase-0 barrier-free.
// -------- Block 256px x 256co, 512 thr, 8 waves of 128px x 64co.  W ring-3, X dbuf.
#define WBYTES 16384      // 256co*32ci*2
#define XBYTES 26112      // 6*68*32*2

// one half (512 chunks) of a 256co x 32ci W tile; 1 chunk/lane
template<int H>
DEVFN void stage_w_half(const u16* __restrict__ wstep, char* dst, int wv, int l){
  int qb = H*512 + wv*64;
  int q  = qb + l;
  int co_l = q >> 2, j = q & 3;
  gload16(wstep + co_l*32 + ((j ^ ((co_l >> 1) & 3)) << 3), dst + qb*16);
  __builtin_amdgcn_sched_barrier(0);
}

// one quarter (chunk C of 4) of a 6row x 68col x 32ci X tile (1632 chunks, dup-wrap)
template<int C>
DEVFN void stage_x_chunk(const u16* __restrict__ xtb, int h0, int cioff, char* dst,
                         int wv, int l){
  int qb = C*512 + wv*64;
  if (qb >= 1632) qb -= 1632;          // wave-uniform dup (same data, benign)
  int q = qb + l;
  int t2 = q >> 2;                     // 0..407 = row*68+col
  int lr = (t2 * 964) >> 16;           // /68, exact for t2<408
  int c  = t2 - lr*68;
  int j  = q & 3;
  gload16(xtb + ((size_t)(h0 + lr)*68 + c)*CIN + cioff + ((j ^ ((c >> 1) & 3)) << 3),
          dst + qb*16);
  __builtin_amdgcn_sched_barrier(0);
}

// one K=32 step t=cb*9+RS.  Phase 0 is BARRIER-FREE (reads target stable
// buffers: W(t) published at step t-1's vmwait+barrier, Xc stable all cb) —
// waves drift within the step, so one wave's MFMA overlaps another's ds_reads.
// Phase 1 keeps the vmwait+barrier (publishes W(t+1), X chunks) + closing barrier
// (guards the W-slot overwrite at t+1 and the X dbuf swap).
template<int RS>
DEVFN void conv_step(int cb, char* ldsW, const char* Xc, char* Xn,
                     const u16* __restrict__ xtb, const u16* __restrict__ wcb, int h0,
                     int wv, int l, int wm, int wn, int l15, int kbq,
                     f32x4 acc[4][8])
{
  constexpr int r = RS/3, s = RS - r*3;
  const char* Wc = ldsW + (RS % 3)*WBYTES;
  char* Wp       = ldsW + ((RS + 2) % 3)*WBYTES;
  const u16* wnext = wcb + (size_t)(cb*9 + RS + 2)*(COUT*32);
  const bool dostage = (RS <= 6) || (cb < 7);

  // ---- phase 0 (no barriers): W all 4 n-frags + X m-frags 0..3 (row wm*2+r) ----
  bf16x8 wf[4], xf[4];
  const int swzA = (kbq ^ ((l15 >> 1) & 3)) << 4;
#pragma unroll
  for (int nf = 0; nf < 4; nf++)
    wf[nf] = *(const bf16x8*)(Wc + (wn*64 + nf*16 + l15)*64 + swzA);
  {
    int row = wm*2 + r;
#pragma unroll
    for (int mf = 0; mf < 4; mf++){
      int c0 = mf*16 + l15 + s;
      xf[mf] = *(const bf16x8*)(Xc + (row*68 + c0)*64 + ((kbq ^ ((c0 >> 1) & 3)) << 4));
    }
  }
  if (dostage) stage_w_half<0>(wnext, Wp, wv, l);
  LGKM0();                         // own reads landed (rule #18: sched_barrier inside)
  __builtin_amdgcn_s_setprio(1);
#pragma unroll
  for (int nf = 0; nf < 4; nf++)
#pragma unroll
    for (int mf = 0; mf < 4; mf++)
      acc[nf][mf] = __builtin_amdgcn_mfma_f32_16x16x32_bf16(wf[nf], xf[mf], acc[nf][mf], 0, 0, 0);
  __builtin_amdgcn_s_setprio(0);

  // ---- phase 1: X m-frags 4..7 (row wm*2+1+r) ----
  {
    int row = wm*2 + 1 + r;
#pragma unroll
    for (int mf = 0; mf < 4; mf++){
      int c0 = mf*16 + l15 + s;
      xf[mf] = *(const bf16x8*)(Xc + (row*68 + c0)*64 + ((kbq ^ ((c0 >> 1) & 3)) << 4));
    }
  }
  if (dostage) stage_w_half<1>(wnext, Wp, wv, l);
  if constexpr (RS <= 3) { if (cb < 7) stage_x_chunk<RS>(xtb, h0, (cb+1)*32, Xn, wv, l); }
  // FIFO identical to R12: keep 2 newest in flight; W(t+1) fully retired.
  if (dostage) { VMWAIT(2); }
  else if constexpr (RS == 7) { VMWAIT(0); }
  BARRIER();                       // publish W(t+1) (+X chunks) to all waves
  LGKM0();
  __builtin_amdgcn_s_setprio(1);
#pragma unroll
  for (int nf = 0; nf < 4; nf++)
#pragma unroll
    for (int mf = 0; mf < 4; mf++)
      acc[nf][mf+4] = __builtin_amdgcn_mfma_f32_16x16x32_bf16(wf[nf], xf[mf], acc[nf][mf+4], 0, 0, 0);
  __builtin_amdgcn_s_setprio(0);
  BARRIER();                       // close step: W-slot overwrite / X-swap guard
}

__global__ __launch_bounds__(512, 2) void k_conv(
    const u16* __restrict__ xt, const u16* __restrict__ wc,
    const float* __restrict__ cbias, float* __restrict__ out, u16* __restrict__ obf,
    float* __restrict__ ssum, float* __restrict__ ssq)
{
  __shared__ char lds[3*WBYTES + 2*XBYTES];   // 101376 -> 1 block/CU
  char* XA = lds + 3*WBYTES;
  char* XB = lds + 3*WBYTES + XBYTES;

  // XCD-contiguous mapping: 512 blocks; xcd owns 2 samples, sample-major order.
  int hw  = blockIdx.x;
  int xcd = hw & 7;
  int i   = hw >> 3;                 // 0..63
  int b   = xcd*2 + (i >> 5);
  int ct  = (i >> 4) & 1;
  int pt  = i & 15;
  int h0  = pt * 4;

  int t = threadIdx.x, l = t & 63, wv = t >> 6;   // 8 waves
  int wm = wv >> 2, wn = wv & 3;                  // px-half, co-quarter
  int l15 = l & 15, kbq = l >> 4;

  const u16* xtb = xt + (size_t)b * 66*68*CIN;
  const u16* wcb = wc + (size_t)(b*NSTEP) * COUT*32 + ct*256*32;

  f32x4 acc[4][8];
#pragma unroll
  for (int nf = 0; nf < 4; nf++)
#pragma unroll
    for (int mf = 0; mf < 8; mf++) acc[nf][mf] = (f32x4){0.f,0.f,0.f,0.f};

  // prologue: X(0)->XA (4 chunks), W(0)->slot0, W(1)->slot1; drain; publish.
  stage_x_chunk<0>(xtb, h0, 0, XA, wv, l);
  stage_x_chunk<1>(xtb, h0, 0, XA, wv, l);
  stage_x_chunk<2>(xtb, h0, 0, XA, wv, l);
  stage_x_chunk<3>(xtb, h0, 0, XA, wv, l);
  stage_w_half<0>(wcb,           lds + 0*WBYTES, wv, l);
  stage_w_half<1>(wcb,           lds + 0*WBYTES, wv, l);
  stage_w_half<0>(wcb + COUT*32, lds + 1*WBYTES, wv, l);
  stage_w_half<1>(wcb + COUT*32, lds + 1*WBYTES, wv, l);
  VMWAIT(0);
  BARRIER();

  for (int cb = 0; cb < 8; cb++){
    const char* Xc = (cb & 1) ? XB : XA;
    char*       Xn = (cb & 1) ? XA : XB;
    conv_step<0>(cb, lds, Xc, Xn, xtb, wcb, h0, wv,l,wm,wn,l15,kbq, acc);
    conv_step<1>(cb, lds, Xc, Xn, xtb, wcb, h0, wv,l,wm,wn,l15,kbq, acc);
    conv_step<2>(cb, lds, Xc, Xn, xtb, wcb, h0, wv,l,wm,wn,l15,kbq, acc);
    conv_step<3>(cb, lds, Xc, Xn, xtb, wcb, h0, wv,l,wm,wn,l15,kbq, acc);
    conv_step<4>(cb, lds, Xc, Xn, xtb, wcb, h0, wv,l,wm,wn,l15,kbq, acc);
    conv_step<5>(cb, lds, Xc, Xn, xtb, wcb, h0, wv,l,wm,wn,l15,kbq, acc);
    conv_step<6>(cb, lds, Xc, Xn, xtb, wcb, h0, wv,l,wm,wn,l15,kbq, acc);
    conv_step<7>(cb, lds, Xc, Xn, xtb, wcb, h0, wv,l,wm,wn,l15,kbq, acc);
    conv_step<8>(cb, lds, Xc, Xn, xtb, wcb, h0, wv,l,wm,wn,l15,kbq, acc);
  }

  // ---- epilogue: bias add, store bf16 (or f32), fused BN partials ----
#pragma unroll
  for (int nf = 0; nf < 4; nf++){
#pragma unroll
    for (int rg = 0; rg < 4; rg++){
      int co = ct*256 + wn*64 + nf*16 + (kbq << 2) + rg;
      float bias = cbias[b*COUT + co];
      float s1 = 0.f, s2 = 0.f;
      size_t base = ((size_t)b * COUT + co) * NPX;
#pragma unroll
      for (int mf = 0; mf < 8; mf++){
        float v = acc[nf][mf][rg] + bias;
        int px = (h0 + wm*2 + (mf >> 2))*64 + (mf & 3)*16 + l15;
        if (obf) obf[base + px] = bf16_rne(v);
        else     out[base + px] = v;
        s1 += v; s2 += v*v;
      }
#pragma unroll
      for (int o = 8; o; o >>= 1){ s1 += __shfl_xor(s1, o); s2 += __shfl_xor(s2, o); }
      if (l15 == 0){ atomicAdd(&ssum[co], s1); atomicAdd(&ssq[co], s2); }
    }
  }
}

// ---------------- finalize BN scale/shift ----------------
__global__ void k_stats(const float* __restrict__ ssum, const float* __restrict__ ssq,
                        const float* __restrict__ gamma, const float* __restrict__ beta,
                        float* __restrict__ sc, float* __restrict__ sh){
  int co = blockIdx.x*256 + threadIdx.x;    // 512
  const float invN = 1.0f / 65536.0f;
  float m  = ssum[co] * invN;
  float var = ssq[co] * invN - m*m;
  float scale = gamma[co] * rsqrtf(var + 1e-5f);
  sc[co] = scale;
  sh[co] = beta[co] - m*scale;
}

// ---------------- normalize + LeakyReLU: f32 in-place variant ----------------
__global__ void k_norm(float* __restrict__ out, const float* __restrict__ sc,
                       const float* __restrict__ sh){
  const int NF4 = (NB*COUT*NPX)/4;          // 8388608
  int idx = blockIdx.x*256 + threadIdx.x;
  float4* o4 = (float4*)out;
  for (int i = idx; i < NF4; i += 2048*256){
    float4 v = o4[i];
    int co = (i >> 10) & 511;
    float a = sc[co], d = sh[co];
    v.x = fmaf(v.x, a, d); v.y = fmaf(v.y, a, d);
    v.z = fmaf(v.z, a, d); v.w = fmaf(v.w, a, d);
    v.x = v.x > 0.f ? v.x : 0.1f*v.x;
    v.y = v.y > 0.f ? v.y : 0.1f*v.y;
    v.z = v.z > 0.f ? v.z : 0.1f*v.z;
    v.w = v.w > 0.f ? v.w : 0.1f*v.w;
    o4[i] = v;
  }
}

// ---------------- normalize + LeakyReLU: bf16 -> f32 variant ----------------
__global__ void k_norm_bf16(const u16* __restrict__ obf, float* __restrict__ out,
                            const float* __restrict__ sc, const float* __restrict__ sh){
  const int NG = (NB*COUT*NPX)/8;           // 4194304
  int idx = blockIdx.x*256 + threadIdx.x;
  for (int g = idx; g < NG; g += 2048*256){
    u16x8 v = *(const u16x8*)(obf + (size_t)g*8);
    int co = (g >> 9) & 511;
    float a = sc[co], d = sh[co];
    float vv[8];
#pragma unroll
    for (int j = 0; j < 8; j++){
      union{ uint32_t u; float f; } c; c.u = ((uint32_t)(u16)v[j]) << 16;
      float w = fmaf(c.f, a, d);
      vv[j] = w > 0.f ? w : 0.1f*w;
    }
    float4* o4 = (float4*)(out + (size_t)g*8);
    o4[0] = (float4){vv[0],vv[1],vv[2],vv[3]};
    o4[1] = (float4){vv[4],vv[5],vv[6],vv[7]};
  }
}

extern "C" void kernel_launch(void* const* d_in, const int* in_sizes, int n_in,
                              void* d_out, int out_size, void* d_ws, size_t ws_size,
                              hipStream_t stream) {
  const float* x     = (const float*)d_in[0];
  const float* ew    = (const float*)d_in[1];
  const float* eb    = (const float*)d_in[2];
  const float* fcw   = (const float*)d_in[3];
  const float* fcb   = (const float*)d_in[4];
  const float* gamma = (const float*)d_in[5];
  const float* beta  = (const float*)d_in[6];
  float* out = (float*)d_out;

  char* ws = (char*)d_ws;
  const size_t XT_BYTES  = (size_t)NB*66*68*CIN*2;         // 36,765,696
  const size_t WC_BYTES  = (size_t)NB*NSTEP*COUT*32*2;     // 37,748,736
  const size_t FL_BYTES  = 65536;
  const size_t OBF_BYTES = (size_t)NB*COUT*NPX*2;          // 67,108,864
  u16* xt = (u16*)ws;
  u16* wc = (u16*)(ws + XT_BYTES);
  float* fbase   = (float*)(ws + XT_BYTES + WC_BYTES);
  float* pooled  = fbase;                 // 4096 (zeroed)
  float* ssum    = fbase + 4096;          // 512  (zeroed)
  float* ssq     = fbase + 4608;          // 512  (zeroed)
  float* routing = fbase + 5120;          // 128
  float* cbias   = fbase + 5248;          // 8192
  float* sc      = fbase + 13440;         // 512
  float* sh      = fbase + 13952;         // 512
  bool use_bf16 = ws_size >= XT_BYTES + WC_BYTES + FL_BYTES + OBF_BYTES;
  u16* obf = use_bf16 ? (u16*)(ws + XT_BYTES + WC_BYTES + FL_BYTES) : (u16*)nullptr;

  hipMemsetAsync(pooled, 0, 5120*sizeof(float), stream);   // pooled+ssum+ssq

  k_halo <<<1056, 256, 0, stream>>>(xt);
  k_xprep<<<4096, 256, 0, stream>>>(x, xt, pooled);
  k_route<<<128,   64, 0, stream>>>(pooled, fcw, fcb, routing);
  k_cbias<<<32,   256, 0, stream>>>(routing, eb, cbias);
  k_wcomb<<<4608, 256, 0, stream>>>(routing, ew, wc);
  k_conv <<<512,  512, 0, stream>>>(xt, wc, cbias, out, obf, ssum, ssq);
  k_stats<<<2,    256, 0, stream>>>(ssum, ssq, gamma, beta, sc, sh);
  if (use_bf16) k_norm_bf16<<<2048, 256, 0, stream>>>(obf, out, sc, sh);
  else          k_norm     <<<2048, 256, 0, stream>>>(out, sc, sh);
}